// Round 12
// baseline (7002.966 us; speedup 1.0000x reference)
//
#include <hip/hip_runtime.h>
#include <hip/hip_bf16.h>
#include <stdint.h>

#define Bn 64
#define Tn 512
#define Hn 1024
#define Ln 4
#define GN 4096
#define POLL_CAP 2000000

typedef __attribute__((ext_vector_type(8))) short bf16x8;
typedef __attribute__((ext_vector_type(4))) float f32x4;
typedef __attribute__((ext_vector_type(4))) unsigned short u16x4;
typedef unsigned long long u64t;

__device__ __forceinline__ unsigned short f2bf(float f) {
  union { float f; unsigned u; } v; v.f = f;
  return (unsigned short)((v.u + 0x7FFFu + ((v.u >> 16) & 1u)) >> 16);
}

template<int AUX>
__device__ __forceinline__ void gloadT(const void* g, void* l) {
  __builtin_amdgcn_global_load_lds((const __attribute__((address_space(1))) void*)g,
                                   (__attribute__((address_space(3))) void*)l, 16, 0, AUX);
}

__device__ __forceinline__ int aload(const int* p) {
  return __hip_atomic_load(p, __ATOMIC_RELAXED, __HIP_MEMORY_SCOPE_AGENT);
}

__device__ __forceinline__ float sigmf(float x) { return 1.0f / (1.0f + expf(-x)); }

// stage one 32KB chunk (64 rows x 512B K-window at ph*512 of 2048B rows)
template<int AUX>
__device__ __forceinline__ void stageChunk(const char* base, int ph, char* buf, int tid) {
#pragma unroll
  for (int j = 0; j < 4; ++j) {
    int o = j * 8192 + tid * 16;
    int row = o >> 9, win = o & 511;
    gloadT<AUX>(base + (size_t)row * 2048 + ph * 512 + (win ^ ((row & 15) << 4)), buf + o);
  }
}
__device__ __forceinline__ void stageAny(int coh, const char* base, int ph, char* buf, int tid) {
  if (coh) stageChunk<17>(base, ph, buf, tid);   // sc0|sc1: LLC-coherent (r6-proven)
  else     stageChunk<0>(base, ph, buf, tid);    // cached (immutable data)
}

// ---------------- prep: lengths + stable descending rank + flag reset ----------------
__global__ __launch_bounds__(256) void prep_kernel(const int* __restrict__ x, int* __restrict__ len,
                                                   int* __restrict__ rank, int* __restrict__ flags) {
  __shared__ int sl[Bn];
  int t = threadIdx.x;
#pragma unroll
  for (int k = 0; k < 4; ++k) flags[t + 256 * k] = 0;
  if (t < Bn) {
    int cnt = 0;
    const int* row = x + (size_t)t * Tn;
    for (int i = 0; i < Tn; ++i) cnt += (row[i] > 0) ? 1 : 0;
    sl[t] = cnt;
  }
  __syncthreads();
  if (t < Bn) {
    int Lb = sl[t], r = 0;
    for (int j = 0; j < Bn; ++j) {
      int lj = sl[j];
      r += ((lj > Lb) || (lj == Lb && j < t)) ? 1 : 0;
    }
    len[t] = Lb;
    rank[t] = r;
  }
}

__global__ void bias_kernel(const float* __restrict__ bih, const float* __restrict__ bhh,
                            float* __restrict__ bias) {
  int i = blockIdx.x * blockDim.x + threadIdx.x;
  if (i < Ln * GN) bias[i] = bih[i] + bhh[i];
}

__global__ __launch_bounds__(256) void embed_kernel(const int* __restrict__ x,
                                                    const float* __restrict__ emb,
                                                    unsigned short* __restrict__ Xemb) {
  int row = blockIdx.x;        // t*64 + b
  int t = row >> 6, b = row & 63;
  int tok = x[(size_t)b * Tn + t];
  f32x4 v = ((const f32x4*)(emb + (size_t)tok * Hn))[threadIdx.x];
  u16x4 p;
#pragma unroll
  for (int u = 0; u < 4; ++u) p[u] = f2bf(v[u]);
  ((u16x4*)(Xemb + (size_t)row * Hn))[threadIdx.x] = p;
}

// init hmask dep-3 slot (read at t=0 as (t-1)&3)
__global__ __launch_bounds__(256) void init_hmask_kernel(const float* __restrict__ h0,
                                                         unsigned short* __restrict__ hmaskB) {
  int i = blockIdx.x * blockDim.x + threadIdx.x;   // L*B*H
  int c = i >> 16, rem = i & 65535;
  hmaskB[(size_t)(c * 4 + 3) * 65536 + rem] = f2bf(h0[i]);
}

// ---------------- persistent kernel: x/h split, self-timed flags, ALL-agent protocol ----------------
// grid 256 x 512. grp=bid&7: grp<4 -> h-block (cell=grp); grp>=4 -> x-block (cell=grp-4)
// slot = bid>>3: owns 128 gate-cols = 4 gates x h-cols [slot*32, slot*32+32) ; x/h slot pairing 1:1
// wave sp: gate sp>>1, col half sp&1
__global__ __launch_bounds__(512, 2) void wavefront_kernel(
    const float* __restrict__ Wih, const float* __restrict__ Whh,
    const float* __restrict__ biasF, const char* __restrict__ Xemb,
    unsigned short* __restrict__ hmaskB, unsigned short* __restrict__ hfresh,
    float* __restrict__ part, const int* __restrict__ len, const int* __restrict__ rankp,
    const float* __restrict__ h0, const float* __restrict__ c0,
    float* __restrict__ outp, float* __restrict__ hF, float* __restrict__ cF,
    int* __restrict__ flags) {
  __shared__ char smem[131072];   // bufs 0/1/2 @0/32768/65536 (exchange reuses buf1), partial @98304
  int tid = threadIdx.x, bid = blockIdx.x;
  int grp = bid & 7;
  int isH = (grp < 4) ? 1 : 0;
  int cell = grp & 3, slot = bid >> 3;
  int sp = tid >> 6, lane = tid & 63, l15 = lane & 15, lk = lane >> 4;
  int* hfarr = flags;        // [4][32] h progress (agent)
  int* xparr = flags + 128;  // [4][32] x progress (agent)

  // ---- W preload: 32 named bf16x8 (on-the-fly f32->bf16), K-slice i -> [i*32, i*32+32) ----
  int j = sp * 16 + l15;
  const float* wrow = (isH ? Whh : Wih) + (size_t)cell * GN * Hn
                    + (size_t)((j >> 5) * 1024 + slot * 32 + (j & 31)) * Hn + lk * 8;
  bf16x8 a0,a1,a2,a3,a4,a5,a6,a7,a8,a9,a10,a11,a12,a13,a14,a15;
  bf16x8 b0,b1,b2,b3,b4,b5,b6,b7,b8,b9,b10,b11,b12,b13,b14,b15;
#define LW(R, I) { f32x4 u0_ = *(const f32x4*)(wrow + (I) * 32);                         \
    f32x4 u1_ = *(const f32x4*)(wrow + (I) * 32 + 4); bf16x8 t_;                          \
    t_[0]=(short)f2bf(u0_[0]); t_[1]=(short)f2bf(u0_[1]); t_[2]=(short)f2bf(u0_[2]);      \
    t_[3]=(short)f2bf(u0_[3]); t_[4]=(short)f2bf(u1_[0]); t_[5]=(short)f2bf(u1_[1]);      \
    t_[6]=(short)f2bf(u1_[2]); t_[7]=(short)f2bf(u1_[3]); R = t_; }
  LW(a0,0)  LW(a1,1)  LW(a2,2)  LW(a3,3)  LW(a4,4)  LW(a5,5)  LW(a6,6)  LW(a7,7)
  LW(a8,8)  LW(a9,9)  LW(a10,10) LW(a11,11) LW(a12,12) LW(a13,13) LW(a14,14) LW(a15,15)
  LW(b0,16) LW(b1,17) LW(b2,18) LW(b3,19) LW(b4,20) LW(b5,21) LW(b6,22) LW(b7,23)
  LW(b8,24) LW(b9,25) LW(b10,26) LW(b11,27) LW(b12,28) LW(b13,29) LW(b14,30) LW(b15,31)
#undef LW

  // ---- epilogue state (h-blocks): thread -> (batch r, 4 h-cols) ----
  int r = tid >> 3, hcl = (tid & 7) * 4;
  int hcg = slot * 32 + hcl;
  f32x4 bIv = {}, bFv = {}, bGv = {}, bOv = {}, hold = {}, cold = {};
  int lenr = 0, rnkr = 0;
  if (isH) {
    const float* bias = biasF + cell * GN;
    bIv = *(const f32x4*)(bias + hcg);
    bFv = *(const f32x4*)(bias + 1024 + hcg);
    bGv = *(const f32x4*)(bias + 2048 + hcg);
    bOv = *(const f32x4*)(bias + 3072 + hcg);
    lenr = len[r]; rnkr = rankp[r];
    hold = *(const f32x4*)(h0 + ((size_t)cell * Bn + r) * Hn + hcg);
    cold = *(const f32x4*)(c0 + ((size_t)cell * Bn + r) * Hn + hcg);
  }

#define PHASE(P, VMSTR, NEXT, R0,R1,R2,R3,R4,R5,R6,R7)                                    \
  {                                                                                       \
    asm volatile("s_waitcnt " VMSTR ::: "memory");                                        \
    __builtin_amdgcn_s_barrier();                                                         \
    if ((NEXT) >= 0) stageAny(coh, inb, (NEXT), smem + ((NEXT) % 3) * 32768, tid);        \
    const char* chunk_ = smem + ((P) % 3) * 32768;                                        \
    _Pragma("unroll")                                                                     \
    for (int ks_ = 0; ks_ < 8; ++ks_) {                                                   \
      int kb_ = ks_ * 64 + lk * 16;                                                       \
      bf16x8 wv_ = (ks_==0?R0:ks_==1?R1:ks_==2?R2:ks_==3?R3:ks_==4?R4:ks_==5?R5:ks_==6?R6:R7); \
      _Pragma("unroll")                                                                   \
      for (int mi_ = 0; mi_ < 4; ++mi_) {                                                 \
        int row_ = mi_ * 16 + l15;                                                        \
        bf16x8 af_ = *(const bf16x8*)(chunk_ + row_ * 512 + (kb_ ^ ((row_ & 15) << 4)));  \
        acc[mi_] = __builtin_amdgcn_mfma_f32_16x16x32_bf16(af_, wv_, acc[mi_], 0, 0, 0);  \
      }                                                                                   \
    }                                                                                     \
  }

#define POLLALL(PTR_EXPR, THR)                                                            \
  for (int it_ = 0; it_ < POLL_CAP; ++it_) {                                              \
    int v_ = aload(PTR_EXPR);                                                             \
    if (__all(v_ >= (THR))) break;                                                        \
    __builtin_amdgcn_s_sleep(1);                                                          \
  }
#define POLLONE(PTR, THR)                                                                 \
  for (int it_ = 0; it_ < POLL_CAP; ++it_) {                                              \
    if (aload(PTR) >= (THR)) break;                                                       \
    __builtin_amdgcn_s_sleep(1);                                                          \
  }

  for (int t = 0; t < Tn; ++t) {
    // ---- dependency polls (thresholds <=0 auto-pass at startup; depths: hmask4/part4/hfresh8) ----
    if (isH) {
      if (sp == 0) { POLLALL(&hfarr[cell * 32 + (lane & 31)], t) }             // peers done t-1
      if (sp == 1 && lane == 0) { POLLONE(&xparr[cell * 32 + slot], t + 1) }   // partial(t) ready
      if (sp == 2 && cell < 3) { POLLALL(&xparr[(cell + 1) * 32 + (lane & 31)], t - 7) } // hfresh slot free
    } else {
      if (sp == 0 && cell > 0) { POLLALL(&hfarr[(cell - 1) * 32 + (lane & 31)], t + 1) } // in(t) ready
      if (sp == 1 && lane == 0) { POLLONE(&hfarr[cell * 32 + slot], t - 3) }   // part slot consumed
    }
    __syncthreads();

    // ---- panel source ----
    const char* inb;
    int coh;
    if (isH) {
      inb = (const char*)hmaskB + (size_t)(cell * 4 + ((t - 1) & 3)) * 131072;  coh = 1;
    } else if (cell == 0) {
      inb = Xemb + (size_t)t * 131072;  coh = 0;   // immutable -> cached
    } else {
      inb = (const char*)hfresh + (size_t)((cell - 1) * 8 + (t & 7)) * 131072;  coh = 1;
    }

    // ---- prologue staging: [h: partial 32KB] + chunks 0,1 ----
    if (isH) {
      const char* psrc = (const char*)part + (size_t)((cell * 4 + (t & 3)) * 32 + slot) * 32768;
#pragma unroll
      for (int jj = 0; jj < 4; ++jj) {
        int o = jj * 8192 + tid * 16;
        gloadT<17>(psrc + o, smem + 98304 + o);
      }
    }
    stageAny(coh, inb, 0, smem, tid);
    stageAny(coh, inb, 1, smem + 32768, tid);

    f32x4 acc[4] = {};
    PHASE(0, "vmcnt(4)", 2, a0,a1,a2,a3,a4,a5,a6,a7)
    PHASE(1, "vmcnt(4)", 3, a8,a9,a10,a11,a12,a13,a14,a15)
    PHASE(2, "vmcnt(4)", -1, b0,b1,b2,b3,b4,b5,b6,b7)
    PHASE(3, "vmcnt(0)", -1, b8,b9,b10,b11,b12,b13,b14,b15)

    // ---- strip exchange -> LDS @32768 ([sp][64][16] f32) ----
    {
      float* ex = (float*)(smem + 32768) + sp * 1024;
#pragma unroll
      for (int mi = 0; mi < 4; ++mi)
#pragma unroll
        for (int jj = 0; jj < 4; ++jj)
          ex[(mi * 16 + lk * 4 + jj) * 16 + l15] = acc[mi][jj];
    }
    __syncthreads();

    if (isH) {
      const float* exf = (const float*)(smem + 32768);
      const float* pf  = (const float*)(smem + 98304);
      f32x4 g4[4];
#pragma unroll
      for (int g = 0; g < 4; ++g) {
        int off = (g * 2 + (hcl >> 4)) * 1024 + r * 16 + (hcl & 15);
        f32x4 e = *(const f32x4*)(exf + off);
        f32x4 p = *(const f32x4*)(pf + off);
#pragma unroll
        for (int u = 0; u < 4; ++u) g4[g][u] = e[u] + p[u];
      }
      bool msk = (t < lenr);
      f32x4 hx;
#pragma unroll
      for (int u = 0; u < 4; ++u) {
        float iv = sigmf(g4[0][u] + bIv[u]);
        float fv = sigmf(g4[1][u] + bFv[u]);
        float gv = tanhf(g4[2][u] + bGv[u]);
        float ov = sigmf(g4[3][u] + bOv[u]);
        float cc = fv * cold[u] + iv * gv;
        float hh = ov * tanhf(cc);
        hx[u] = hh;
        cold[u] = msk ? cc : cold[u];
        hold[u] = msk ? hh : hold[u];
      }
      u64t hb64 = (u64t)f2bf(hold[0]) | ((u64t)f2bf(hold[1]) << 16)
                | ((u64t)f2bf(hold[2]) << 32) | ((u64t)f2bf(hold[3]) << 48);
      u64t xb64 = (u64t)f2bf(hx[0]) | ((u64t)f2bf(hx[1]) << 16)
                | ((u64t)f2bf(hx[2]) << 32) | ((u64t)f2bf(hx[3]) << 48);
      u64t* hmW = (u64t*)(hmaskB + (size_t)(cell * 4 + (t & 3)) * 65536 + (size_t)r * Hn + hcg);
      u64t* hfW = (u64t*)(hfresh + (size_t)(cell * 8 + (t & 7)) * 65536 + (size_t)r * Hn + hcg);
      __hip_atomic_store(hmW, hb64, __ATOMIC_RELAXED, __HIP_MEMORY_SCOPE_AGENT);
      __hip_atomic_store(hfW, xb64, __ATOMIC_RELAXED, __HIP_MEMORY_SCOPE_AGENT);
      if (cell == 3) {
        f32x4 o4;
#pragma unroll
        for (int u = 0; u < 4; ++u) o4[u] = msk ? hx[u] : 0.0f;
        *(f32x4*)(outp + ((size_t)r * Tn + t) * Hn + hcg) = o4;
      }
      __syncthreads();     // drains vmcnt(0) per wave -> stores at LLC before flag
      if (tid == 0)
        __hip_atomic_store(&hfarr[cell * 32 + slot], t + 1, __ATOMIC_RELAXED,
                           __HIP_MEMORY_SCOPE_AGENT);
    } else {
      // publish partial (32KB f32) to part[cell][t&3][slot] at agent scope
      float* pdst = part + (size_t)((cell * 4 + (t & 3)) * 32 + slot) * 8192;
      const u64t* src = (const u64t*)(smem + 32768) + tid * 8;
      u64t* dst = (u64t*)pdst + tid * 8;
#pragma unroll
      for (int ii = 0; ii < 8; ++ii)
        __hip_atomic_store(&dst[ii], src[ii], __ATOMIC_RELAXED, __HIP_MEMORY_SCOPE_AGENT);
      __syncthreads();
      if (tid == 0)
        __hip_atomic_store(&xparr[cell * 32 + slot], t + 1, __ATOMIC_RELAXED,
                           __HIP_MEMORY_SCOPE_AGENT);
    }
  }
#undef PHASE
#undef POLLALL
#undef POLLONE

  // ---- final state writeback (rank-permuted; state lived in registers) ----
  if (isH) {
    *(f32x4*)(hF + ((size_t)cell * Bn + rnkr) * Hn + hcg) = hold;
    *(f32x4*)(cF + ((size_t)cell * Bn + rnkr) * Hn + hcg) = cold;
  }
}

extern "C" void kernel_launch(void* const* d_in, const int* in_sizes, int n_in,
                              void* d_out, int out_size, void* d_ws, size_t ws_size,
                              hipStream_t stream) {
  const int*   x   = (const int*)d_in[0];
  const float* h0  = (const float*)d_in[1];
  const float* c0  = (const float*)d_in[2];
  const float* emb = (const float*)d_in[3];
  const float* Wih = (const float*)d_in[4];
  const float* Whh = (const float*)d_in[5];
  const float* bih = (const float*)d_in[6];
  const float* bhh = (const float*)d_in[7];
  float* out = (float*)d_out;

  char* ws = (char*)d_ws;
  unsigned short* Xemb   = (unsigned short*)ws;                  // 67108864 B
  float*          part   = (float*)(ws + 67108864);              // 16777216 B (4 cells x 4 depth x 1MB)
  unsigned short* hmaskB = (unsigned short*)(ws + 83886080);     // 2097152 B (4 cells x 4 depth)
  unsigned short* hfresh = (unsigned short*)(ws + 85983232);     // 4194304 B (4 cells x 8 depth)
  float*          biasF  = (float*)(ws + 90177536);              // 65536 B
  int*            leni   = (int*)(ws + 90243072);
  int*            ranki  = (int*)(ws + 90243328);
  int*            flags  = (int*)(ws + 90243584);                // 4096 B

  prep_kernel<<<1, 256, 0, stream>>>(x, leni, ranki, flags);
  bias_kernel<<<64, 256, 0, stream>>>(bih, bhh, biasF);
  embed_kernel<<<Tn * Bn, 256, 0, stream>>>(x, emb, Xemb);
  init_hmask_kernel<<<1024, 256, 0, stream>>>(h0, hmaskB);

  float* hFbase = out + (size_t)Bn * Tn * Hn;
  float* cFbase = hFbase + (size_t)Ln * Bn * Hn;

  wavefront_kernel<<<256, 512, 0, stream>>>(
      Wih, Whh, biasF, (const char*)Xemb, hmaskB, hfresh, part,
      leni, ranki, h0, c0, out, hFbase, cFbase, flags);
}

// Round 13
// 4825.581 us; speedup vs baseline: 1.4512x; 1.4512x over previous
//
#include <hip/hip_runtime.h>
#include <hip/hip_bf16.h>
#include <stdint.h>

#define Bn 64
#define Tn 512
#define Hn 1024
#define Ln 4
#define GN 4096   // 4*H
#define NDIAG (Tn + Ln - 1)

typedef __attribute__((ext_vector_type(8))) short bf16x8;
typedef __attribute__((ext_vector_type(4))) float f32x4;
typedef __attribute__((ext_vector_type(4))) unsigned short u16x4;

__device__ __forceinline__ unsigned short f2bf(float f) {
  union { float f; unsigned u; } v; v.f = f;
  return (unsigned short)((v.u + 0x7FFFu + ((v.u >> 16) & 1u)) >> 16);
}

// cached (normal) global->LDS 16B
__device__ __forceinline__ void gload16(const void* g, void* l) {
  __builtin_amdgcn_global_load_lds((const __attribute__((address_space(1))) void*)g,
                                   (__attribute__((address_space(3))) void*)l, 16, 0, 0);
}
// device-coherent global->LDS 16B: aux = sc0|sc1 -> bypass L1/L2, read LLC
__device__ __forceinline__ void gload16c(const void* g, void* l) {
  __builtin_amdgcn_global_load_lds((const __attribute__((address_space(1))) void*)g,
                                   (__attribute__((address_space(3))) void*)l, 16, 0, 17);
}

__device__ __forceinline__ float sigmf(float x) { return 1.0f / (1.0f + expf(-x)); }

// ---------------- prep: lengths + stable descending rank + barrier state reset ----------------
__global__ __launch_bounds__(256) void prep_kernel(const int* __restrict__ x, int* __restrict__ len,
                                                   int* __restrict__ rank, int* __restrict__ arrive,
                                                   int* __restrict__ gen) {
  __shared__ int sl[Bn];
  int t = threadIdx.x;
  arrive[t] = 0;                  // 256 slots cleared (deterministic each call)
  if (t == 0) *gen = 0;
  if (t < Bn) {
    int cnt = 0;
    const int* row = x + (size_t)t * Tn;
    for (int i = 0; i < Tn; ++i) cnt += (row[i] > 0) ? 1 : 0;
    sl[t] = cnt;
  }
  __syncthreads();
  if (t < Bn) {
    int Lb = sl[t], r = 0;
    for (int j = 0; j < Bn; ++j) {
      int lj = sl[j];
      r += ((lj > Lb) || (lj == Lb && j < t)) ? 1 : 0;
    }
    len[t] = Lb;
    rank[t] = r;
  }
}

// ---------------- bias fold ----------------
__global__ void bias_kernel(const float* __restrict__ bih, const float* __restrict__ bhh,
                            float* __restrict__ bias) {
  int i = blockIdx.x * blockDim.x + threadIdx.x;
  if (i < Ln * GN) bias[i] = bih[i] + bhh[i];
}

// ---------------- cast + permute weights into W_cat block layout ----------------
// Wlay[l][n][k]: n = bn*64 + j, j = strip*16 + hcl
// gate row g = strip*1024 + bn*16 + hcl ; k<1024 -> Wih[g][k], k>=1024 -> Whh[g][k-1024]
__global__ __launch_bounds__(256) void cast_w_kernel(const float* __restrict__ Wih,
                                                     const float* __restrict__ Whh,
                                                     unsigned short* __restrict__ Wlay) {
  size_t i = (size_t)blockIdx.x * blockDim.x + threadIdx.x; // (l, n, k4)
  int k4 = (int)(i & 511);
  int n  = (int)((i >> 9) & 4095);
  int l  = (int)(i >> 21);
  int bn = n >> 6, j = n & 63;
  int strip = j >> 4, hcl = j & 15;
  int g = strip * 1024 + bn * 16 + hcl;
  int k = k4 * 4;
  f32x4 v;
  if (k < 1024) v = *(const f32x4*)(Wih + ((size_t)l * GN + g) * Hn + k);
  else          v = *(const f32x4*)(Whh + ((size_t)l * GN + g) * Hn + (k - 1024));
  u16x4 pv;
#pragma unroll
  for (int u = 0; u < 4; ++u) pv[u] = f2bf(v[u]);
  *(u16x4*)(Wlay + i * 4) = pv;
}

// ---------------- embedding gather ----------------
__global__ __launch_bounds__(256) void embed_kernel(const int* __restrict__ x,
                                                    const float* __restrict__ emb,
                                                    unsigned short* __restrict__ Xemb) {
  int row = blockIdx.x;        // t*64 + b
  int t = row >> 6, b = row & 63;
  int tok = x[(size_t)b * Tn + t];
  f32x4 v = ((const f32x4*)(emb + (size_t)tok * Hn))[threadIdx.x];
  u16x4 p;
#pragma unroll
  for (int u = 0; u < 4; ++u) p[u] = f2bf(v[u]);
  ((u16x4*)(Xemb + (size_t)row * Hn))[threadIdx.x] = p;
}

// ---------------- init hmask (both parities) ----------------
__global__ __launch_bounds__(256) void init_hmask_kernel(const float* __restrict__ h0,
                                                         unsigned short* __restrict__ hmask) {
  int i = blockIdx.x * blockDim.x + threadIdx.x;
  unsigned short us = f2bf(h0[i]);
  hmask[i] = us;
  hmask[Ln * Bn * Hn + i] = us;
}

// stage one 16KB chunk: 64 rows x 256B window at byte-col p*256 of 2048B rows
__device__ __forceinline__ void stage_chunk(const char* base, int p, char* lbuf, int tid, bool coh) {
#pragma unroll
  for (int j = 0; j < 2; ++j) {
    int o = j * 8192 + tid * 16;
    int row = o >> 8, win = o & 255;
    const char* src = base + (size_t)row * 2048 + p * 256 + (win ^ ((row & 7) << 4));
    if (coh) gload16c(src, lbuf + o);
    else     gload16(src, lbuf + o);
  }
}

// ---------------- persistent wavefront: W in regs, fence-free coherent protocol ----------------
// grid 256 blocks x 512 threads (8 waves = 4 gate strips x 2 K-halves), 2 waves/SIMD
// cell = (bid&7)>>1 (XCD-paired), bn = (bid&1)*32 + (bid>>3)
__global__ __launch_bounds__(512, 2) void wavefront_kernel(
    const char* __restrict__ Wlay, const float* __restrict__ biasF,
    const char* __restrict__ Xemb,
    unsigned short* __restrict__ hmask, unsigned short* __restrict__ hfresh,
    const int* __restrict__ len, const int* __restrict__ rankp,
    const float* __restrict__ h0, const float* __restrict__ c0,
    float* __restrict__ outp, float* __restrict__ hF, float* __restrict__ cF,
    int* __restrict__ arrive, int* __restrict__ gen) {
  __shared__ char smem[65536];   // 4 staging bufs (kh,parity) 16KB each; exchange reuses par0 bufs
  int tid = threadIdx.x, bid = blockIdx.x;
  int cell = (bid & 7) >> 1;
  int bn = (bid & 1) * 32 + (bid >> 3);
  int w = tid >> 6, lane = tid & 63, l15 = lane & 15, lk = lane >> 4;
  int kh = w >> 2, s = w & 3;

  // one-time W preload: wave (s,kh) holds rows s*16+l15, K-half kh -> 32 bf16x8 = 128 VGPR
  bf16x8 wreg[32];
  {
    const char* wrow = Wlay + ((size_t)((cell * 64 + bn) * 64 + s * 16 + l15)) * 4096
                       + kh * 2048 + lk * 16;
#pragma unroll
    for (int i = 0; i < 32; ++i)
      wreg[i] = *(const bf16x8*)(wrow + i * 64);
  }

  // per-thread epilogue state (threads 0-255 only)
  int r = tid >> 2;
  int c0i = (tid & 3) << 2;
  int hc = bn * 16 + c0i;
  f32x4 bI = {}, bF = {}, bG = {}, bO = {}, hold = {}, cold = {};
  int lenr = 0, rnkr = 0;
  if (tid < 256) {
    const float* bias = biasF + cell * GN;
    bI = *(const f32x4*)(bias + hc);
    bF = *(const f32x4*)(bias + 1024 + hc);
    bG = *(const f32x4*)(bias + 2048 + hc);
    bO = *(const f32x4*)(bias + 3072 + hc);
    lenr = len[r];
    rnkr = rankp[r];
    hold = *(const f32x4*)(h0 + ((size_t)cell * Bn + r) * Hn + hc);
    cold = *(const f32x4*)(c0 + ((size_t)cell * Bn + r) * Hn + hc);
  }

  for (int d = 0; d < NDIAG; ++d) {
    int t = d - cell;
    if (t >= 0 && t < Tn) {
      int p = d & 1;
      bool cohLo = (cell != 0);
      const char* inbase = (cell == 0)
          ? (Xemb + (size_t)t * (Bn * Hn * 2))
          : (const char*)(hfresh + ((size_t)p * Ln + (cell - 1)) * (Bn * Hn));
      const char* hmbase = (const char*)(hmask + ((size_t)p * Ln + cell) * (Bn * Hn));
      unsigned short* hmW = hmask + ((size_t)(p ^ 1) * Ln + cell) * (Bn * Hn);
      unsigned short* hfW = hfresh + ((size_t)(p ^ 1) * Ln + cell) * (Bn * Hn);

      f32x4 acc[4] = {};
      stage_chunk(inbase, 0, smem + 0 * 16384, tid, cohLo);       // (kh0, par0)
      stage_chunk(hmbase, 0, smem + 2 * 16384, tid, true);        // (kh1, par0)
#pragma unroll
      for (int ph = 0; ph < 8; ++ph) {
        __syncthreads();                 // phase ph staged; compute ph-1 done
        if (ph < 7) {
          int par = (ph + 1) & 1;
          stage_chunk(inbase, ph + 1, smem + (0 * 2 + par) * 16384, tid, cohLo);
          stage_chunk(hmbase, ph + 1, smem + (1 * 2 + par) * 16384, tid, true);
        }
        const char* lb = smem + (kh * 2 + (ph & 1)) * 16384;
#pragma unroll
        for (int ksl = 0; ksl < 4; ++ksl) {
#pragma unroll
          for (int mi = 0; mi < 4; ++mi) {
            int row = mi * 16 + l15;
            bf16x8 afr = *(const bf16x8*)(lb + row * 256 + ((ksl * 64 + lk * 16) ^ ((row & 7) << 4)));
            acc[mi] = __builtin_amdgcn_mfma_f32_16x16x32_bf16(afr, wreg[ph * 4 + ksl],
                                                              acc[mi], 0, 0, 0);
          }
        }
      }

      // exchange: kh half -> par0 buf regions ([0,16K) and [32K,48K)), strip-major [64][16] f32
      float* ex = (float*)smem + kh * 8192 + s * 1024;
#pragma unroll
      for (int mi = 0; mi < 4; ++mi)
#pragma unroll
        for (int j = 0; j < 4; ++j)
          ex[(mi * 16 + lk * 4 + j) * 16 + l15] = acc[mi][j];
      __syncthreads();

      if (tid < 256) {
        float* smf = (float*)smem;
        f32x4 sI = *(const f32x4*)(smf + r * 16 + c0i)        + *(const f32x4*)(smf + 8192 + r * 16 + c0i);
        f32x4 sF = *(const f32x4*)(smf + 1024 + r * 16 + c0i) + *(const f32x4*)(smf + 9216 + r * 16 + c0i);
        f32x4 sG = *(const f32x4*)(smf + 2048 + r * 16 + c0i) + *(const f32x4*)(smf + 10240 + r * 16 + c0i);
        f32x4 sO = *(const f32x4*)(smf + 3072 + r * 16 + c0i) + *(const f32x4*)(smf + 11264 + r * 16 + c0i);
        bool msk = (t < lenr);
        f32x4 hx;
#pragma unroll
        for (int u = 0; u < 4; ++u) {
          float iv = sigmf(sI[u] + bI[u]);
          float fv = sigmf(sF[u] + bF[u]);
          float gv = tanhf(sG[u] + bG[u]);
          float ov = sigmf(sO[u] + bO[u]);
          float cc = fv * cold[u] + iv * gv;
          float hh = ov * tanhf(cc);
          hx[u] = hh;
          cold[u] = msk ? cc : cold[u];
          hold[u] = msk ? hh : hold[u];
        }
        unsigned hb01 = (unsigned)f2bf(hold[0]) | ((unsigned)f2bf(hold[1]) << 16);
        unsigned hb23 = (unsigned)f2bf(hold[2]) | ((unsigned)f2bf(hold[3]) << 16);
        unsigned xb01 = (unsigned)f2bf(hx[0]) | ((unsigned)f2bf(hx[1]) << 16);
        unsigned xb23 = (unsigned)f2bf(hx[2]) | ((unsigned)f2bf(hx[3]) << 16);
        unsigned* hm32 = (unsigned*)(hmW + (size_t)r * Hn + hc);
        unsigned* hf32p = (unsigned*)(hfW + (size_t)r * Hn + hc);
        __hip_atomic_store(hm32,     hb01, __ATOMIC_RELAXED, __HIP_MEMORY_SCOPE_AGENT);
        __hip_atomic_store(hm32 + 1, hb23, __ATOMIC_RELAXED, __HIP_MEMORY_SCOPE_AGENT);
        __hip_atomic_store(hf32p,     xb01, __ATOMIC_RELAXED, __HIP_MEMORY_SCOPE_AGENT);
        __hip_atomic_store(hf32p + 1, xb23, __ATOMIC_RELAXED, __HIP_MEMORY_SCOPE_AGENT);
        if (cell == Ln - 1) {
          f32x4 o4;
#pragma unroll
          for (int u = 0; u < 4; ++u) o4[u] = msk ? hx[u] : 0.0f;
          *(f32x4*)(outp + ((size_t)r * Tn + t) * Hn + hc) = o4;
        }
      }
    }

    // ---- store-based distributed barrier (no fences, no RMW) ----
    __syncthreads();    // drains all waves' vmcnt -> agent stores are at LLC
    if (tid == 0)
      __hip_atomic_store(&arrive[bid], d + 1, __ATOMIC_RELAXED, __HIP_MEMORY_SCOPE_AGENT);
    if (bid == 0) {
      if (tid < 256) {
        while (__hip_atomic_load(&arrive[tid], __ATOMIC_RELAXED, __HIP_MEMORY_SCOPE_AGENT) <= d)
          __builtin_amdgcn_s_sleep(1);
      }
      __syncthreads();
      if (tid == 0)
        __hip_atomic_store(gen, d + 1, __ATOMIC_RELAXED, __HIP_MEMORY_SCOPE_AGENT);
    } else {
      if (tid == 0) {
        while (__hip_atomic_load(gen, __ATOMIC_RELAXED, __HIP_MEMORY_SCOPE_AGENT) <= d)
          __builtin_amdgcn_s_sleep(1);
      }
      __syncthreads();
    }
    asm volatile("" ::: "memory");
  }

  // final state writeback with rank permutation (state lived in registers)
  if (tid < 256) {
    *(f32x4*)(hF + ((size_t)cell * Bn + rnkr) * Hn + hc) = hold;
    *(f32x4*)(cF + ((size_t)cell * Bn + rnkr) * Hn + hc) = cold;
  }
}

extern "C" void kernel_launch(void* const* d_in, const int* in_sizes, int n_in,
                              void* d_out, int out_size, void* d_ws, size_t ws_size,
                              hipStream_t stream) {
  const int*   x   = (const int*)d_in[0];
  const float* h0  = (const float*)d_in[1];
  const float* c0  = (const float*)d_in[2];
  const float* emb = (const float*)d_in[3];
  const float* Wih = (const float*)d_in[4];
  const float* Whh = (const float*)d_in[5];
  const float* bih = (const float*)d_in[6];
  const float* bhh = (const float*)d_in[7];
  float* out = (float*)d_out;

  char* ws = (char*)d_ws;
  unsigned short* Wlay  = (unsigned short*)ws;                   // 67108864 B
  float*          biasF = (float*)(ws + 67108864);               // 65536 B
  unsigned short* Xemb  = (unsigned short*)(ws + 67174400);      // 67108864 B
  unsigned short* hmask = (unsigned short*)(ws + 134283264);     // 1048576 B (2 parities)
  unsigned short* hfresh= (unsigned short*)(ws + 135331840);     // 1048576 B
  int*            leni  = (int*)(ws + 136380416);
  int*            ranki = (int*)(ws + 136380672);
  int*            arrv  = (int*)(ws + 136380928);                // 256 arrive slots
  int*            genp  = (int*)(ws + 136381952);                // generation word

  prep_kernel<<<1, 256, 0, stream>>>(x, leni, ranki, arrv, genp);
  bias_kernel<<<64, 256, 0, stream>>>(bih, bhh, biasF);
  cast_w_kernel<<<32768, 256, 0, stream>>>(Wih, Whh, Wlay);
  embed_kernel<<<Tn * Bn, 256, 0, stream>>>(x, emb, Xemb);
  init_hmask_kernel<<<1024, 256, 0, stream>>>(h0, hmask);

  float* hFbase = out + (size_t)Bn * Tn * Hn;
  float* cFbase = hFbase + (size_t)Ln * Bn * Hn;

  wavefront_kernel<<<256, 512, 0, stream>>>(
      (const char*)Wlay, biasF, (const char*)Xemb, hmask, hfresh,
      leni, ranki, h0, c0, out, hFbase, cFbase, arrv, genp);
}